// Round 5
// baseline (83.723 us; speedup 1.0000x reference)
//
#include <hip/hip_runtime.h>
#include <math.h>

#define GDIM 640
#define NDIM 320
#define NB 8
#define NM 200000
#define KROWS 643            // padded kbuf rows: logical kx = -1 .. 641
#define KSTRIDE 644          // padded kbuf row stride (16B-aligned)
#define PI_F 3.14159265358979323846f

// ---------- Bessel I0 (Abramowitz & Stegun 9.8.1/9.8.2, |err| < 2e-7) ----------
__device__ __forceinline__ float bessel_i0f(float x) {
    if (x < 3.75f) {
        float t = x * (1.0f / 3.75f);
        t *= t;
        return 1.0f + t * (3.5156229f + t * (3.0899424f + t * (1.2067492f +
                     t * (0.2659732f + t * (0.0360768f + t * 0.0045813f)))));
    }
    float t = 3.75f / x;
    float p = 0.39894228f + t * (0.01328592f + t * (0.00225319f + t * (-0.00157565f +
              t * (0.00916281f + t * (-0.02057706f + t * (0.02635537f +
              t * (-0.01647633f + t * 0.00392377f)))))));
    return p * __expf(x) * rsqrtf(x);
}

// ---------- deapodization 1/c helper ----------
__device__ __forceinline__ float deapod_c(int i, float beta2) {
    float xs = (float)(i - NDIM / 2) * (1.0f / (float)GDIM);
    float p = PI_F * 3.0f * xs;
    float arg = beta2 - p * p;
    float s = sqrtf(fabsf(arg));
    if (arg > 0.0f) return sinhf(s) / s;
    return (s < 1e-12f) ? 1.0f : sinf(s) / s;   // not reached for these params
}

// ---------- Kaiser-Bessel kernel weight ----------
__device__ __forceinline__ float kbw(float d, float beta) {
    if (fabsf(d) > 1.5f) return 0.0f;
    float u = d * (2.0f / 3.0f);
    float t = 1.0f - u * u;
    t = fmaxf(t, 0.0f);
    return bessel_i0f(beta * sqrtf(t));
}

__device__ __forceinline__ float2 cmul(float2 a, float2 b) {
    return make_float2(a.x * b.x - a.y * b.y, a.x * b.y + a.y * b.x);
}

// ---------- 640-point FFT, in-wave shuffle version ----------
// lds[0..639]: input natural order; on return lds holds fftshifted spectrum.
// blockDim.x == 320 (5 waves). Wave f computes the k1=f radix-5 branch, then a
// 128-pt radix-2 DIF FFT fully in registers (2 complex per lane, shfl_xor
// butterflies). Contains 2 __syncthreads; lds valid for all threads on return.
__device__ __forceinline__ void fft640_wave(float2* lds, int tid) {
    const int f = tid >> 6;         // wave id = k1
    const int L = tid & 63;
    float sw, cw;

    // radix-5 combine: y[b] = sum_a x[a*128+b] * w5^(a*f), w5 = exp(-2pi i f/5)
    __sincosf(-2.0f * PI_F * (float)f * 0.2f, &sw, &cw);
    const float2 w5 = make_float2(cw, sw);
    float2 A = make_float2(0.0f, 0.0f), B = make_float2(0.0f, 0.0f);
    float2 wa = make_float2(1.0f, 0.0f);
#pragma unroll
    for (int a = 0; a < 5; ++a) {
        float2 xa = lds[a * 128 + L];
        float2 xb = lds[a * 128 + L + 64];
        A.x += xa.x * wa.x - xa.y * wa.y;  A.y += xa.x * wa.y + xa.y * wa.x;
        B.x += xb.x * wa.x - xb.y * wa.y;  B.y += xb.x * wa.y + xb.y * wa.x;
        wa = cmul(wa, w5);
    }
    // inter-stage twiddle W640^(b*f)
    __sincosf(-2.0f * PI_F * (float)(L * f) * (1.0f / 640.0f), &sw, &cw);
    A = cmul(A, make_float2(cw, sw));
    __sincosf(-2.0f * PI_F * (float)((L + 64) * f) * (1.0f / 640.0f), &sw, &cw);
    B = cmul(B, make_float2(cw, sw));

    // 128-pt DIF stage h=64: in-lane between A (pos L) and B (pos L+64)
    {
        float2 s = make_float2(A.x + B.x, A.y + B.y);
        float2 d = make_float2(A.x - B.x, A.y - B.y);
        __sincosf(-PI_F * (float)L * (1.0f / 64.0f), &sw, &cw);
        B = cmul(d, make_float2(cw, sw));
        A = s;
    }
    // stages h=32..1: cross-lane via shfl_xor; A and B share twiddles
#pragma unroll
    for (int h = 32; h >= 1; h >>= 1) {
        const int jj = L & (h - 1);
        __sincosf(-PI_F * (float)jj * (1.0f / (float)h), &sw, &cw);
        const float2 w = make_float2(cw, sw);
        float2 Ao, Bo;
        Ao.x = __shfl_xor(A.x, h, 64); Ao.y = __shfl_xor(A.y, h, 64);
        Bo.x = __shfl_xor(B.x, h, 64); Bo.y = __shfl_xor(B.y, h, 64);
        if ((L & h) == 0) {
            A = make_float2(A.x + Ao.x, A.y + Ao.y);
            B = make_float2(B.x + Bo.x, B.y + Bo.y);
        } else {
            A = cmul(make_float2(Ao.x - A.x, Ao.y - A.y), w);
            B = cmul(make_float2(Bo.x - B.x, Bo.y - B.y), w);
        }
    }

    __syncthreads();   // all radix-5 reads of lds complete before overwrite

    // position p holds output k2 = rev7(p): A -> k2 = 2*rev6(L), B -> +1.
    // composite k = f + 5*k2, fftshift ks = (k+320)%640
    const int e = (int)(__brev((unsigned)L) >> 26);
    const int ka = f + 10 * e;
    const int kb = ka + 5;
    const int ksa = (ka >= 320) ? (ka - 320) : (ka + 320);
    const int ksb = (kb >= 320) ? (kb - 320) : (kb + 320);
    lds[ksa] = A;
    lds[ksb] = B;
    __syncthreads();
}

// ---------- Pass A: deapod + pad + ifftshift + FFT over x (non-zero rows only) ----------
// Compact storage: buf1c[b][r][kxs], r = 0..319 <-> ifftshifted row y = (r<160)? r : r+320.
__global__ __launch_bounds__(320) void pass_a(const float* __restrict__ x_re,
                                              const float* __restrict__ x_im,
                                              float2* __restrict__ buf1c,
                                              float beta2) {
    __shared__ float2 lds[640];
    const int b = blockIdx.y;
    const int r = blockIdx.x;          // compact row 0..319
    const int tid = threadIdx.x;

    const int ry = (r < 160) ? (r + 160) : (r - 160);   // source image row 0..319
    const float cy = deapod_c(ry, beta2);
    const float scale = 1.0f / (cy * (float)GDIM);

    for (int i = tid; i < GDIM; i += 320) {
        int xx = (i >= 320) ? (i - 320) : (i + 320);
        float2 v = make_float2(0.0f, 0.0f);
        if (xx >= 160 && xx < 480) {
            int rx = xx - 160;
            float cx = deapod_c(rx, beta2);
            float sc = scale / cx;
            size_t off = ((size_t)b * NDIM + ry) * NDIM + rx;
            v.x = x_re[off] * sc;
            v.y = x_im[off] * sc;
        }
        lds[i] = v;
    }
    __syncthreads();

    fft640_wave(lds, tid);

    float2* dst = buf1c + ((size_t)b * NDIM + r) * GDIM;
    for (int i = tid; i < GDIM; i += 320) dst[i] = lds[i];
}

// ---------- Pass B: FFT over y, 4 columns per block, padded+halo output ----------
// kbuf layout [b][pr][pc], pr = kx+1 (rows -1..641), pc = ky+1 (cols -1..641).
__global__ __launch_bounds__(320) void pass_b(const float2* __restrict__ buf1c,
                                              float2* __restrict__ kbuf) {
    __shared__ float2 colsT[4][648];   // stride 648 to spread banks
    const int b = blockIdx.y;
    const int kxs0 = blockIdx.x * 4;
    const int tid = threadIdx.x;

    // coalesced load: thread (r = t>>2, c = t&3) reads 32B-contiguous groups
    for (int base = 0; base < NDIM; base += 80) {
        int r = base + (tid >> 2);
        int c = tid & 3;
        float2 v = buf1c[((size_t)b * NDIM + r) * GDIM + kxs0 + c];
        int y = (r < 160) ? r : (r + 320);       // compact -> ifftshifted y
        colsT[c][y] = v;
    }
    // zero the padded middle y = 160..479 (4 cols x 320)
    for (int i = tid; i < 1280; i += 320) {
        colsT[i & 3][160 + (i >> 2)] = make_float2(0.0f, 0.0f);
    }
    __syncthreads();

#pragma unroll
    for (int c = 0; c < 4; ++c) {
        fft640_wave(&colsT[c][0], tid);
    }

    // store all 4 columns + wrap halos
    float2* kbb = kbuf + (size_t)b * KROWS * KSTRIDE;
#pragma unroll
    for (int c = 0; c < 4; ++c) {
        const int kxs = kxs0 + c;
        int prs[2];
        int nduprow = 1;
        prs[0] = kxs + 1;
        if (kxs == 639) { prs[1] = 0;   nduprow = 2; }
        if (kxs == 0)   { prs[1] = 641; nduprow = 2; }
        if (kxs == 1)   { prs[1] = 642; nduprow = 2; }
        for (int rr = 0; rr < nduprow; ++rr) {
            float2* dst = kbb + (size_t)prs[rr] * KSTRIDE;
            for (int i = tid; i < GDIM; i += 320) dst[1 + i] = colsT[c][i];
            if (tid == 0) {
                dst[0]   = colsT[c][639];   // col -1  = wrap of ky 639
                dst[641] = colsT[c][0];     // col 640 = wrap of ky 0
                dst[642] = colsT[c][1];     // col 641 = wrap of ky 1
            }
        }
    }
}

// ---------- Gather: 3x3 KB interpolation + sqrt(dcf), 1 sample/thread ----------
// b = blockIdx.x & 7 keeps each XCD's L2 on one batch's kbuf slice (3.3 MB < 4 MB).
#define GBLK_PER_B ((NM + 255) / 256)      // 782
__global__ __launch_bounds__(256) void gather_kernel(const float* __restrict__ traj,
                                                     const float* __restrict__ dcf,
                                                     const float2* __restrict__ kbuf,
                                                     float2* __restrict__ out,
                                                     float beta) {
    const int bid = blockIdx.x;
    const int b = bid & 7;
    const int m = (bid >> 3) * 256 + threadIdx.x;
    if (m >= NM) return;

    const float tx = traj[((size_t)b * 2 + 0) * NM + m];
    const float ty = traj[((size_t)b * 2 + 1) * NM + m];
    const float cx = (tx + 0.5f) * (float)GDIM;
    const float cy = (ty + 0.5f) * (float)GDIM;
    const int bxi = (int)floorf(cx - 1.0f);   // -1 .. 639
    const int byi = (int)floorf(cy - 1.0f);
    const float fx = cx - (float)bxi;         // d at tap 0, in [1,2)
    const float fy = cy - (float)byi;

    const float2* __restrict__ kb = kbuf + (size_t)b * KROWS * KSTRIDE;
    const int pc0 = byi + 1;                  // 0..640
    const int odd = pc0 & 1;

    // issue all 6 aligned 16B loads first
    float4 A[3], Bv[3];
#pragma unroll
    for (int lx = 0; lx < 3; ++lx) {
        size_t e = ((size_t)(bxi + 1 + lx) * KSTRIDE + (size_t)pc0) & ~(size_t)1;
        const float4* p = (const float4*)(kb + e);
        A[lx] = p[0];
        Bv[lx] = p[1];
    }

    // weights while loads are in flight
    float wx[3], wy[3];
#pragma unroll
    for (int l = 0; l < 3; ++l) {
        wx[l] = kbw(fx - (float)l, beta);
        wy[l] = kbw(fy - (float)l, beta);
    }

    float accx = 0.0f, accy = 0.0f;
#pragma unroll
    for (int lx = 0; lx < 3; ++lx) {
        float t0x = odd ? A[lx].z : A[lx].x;
        float t0y = odd ? A[lx].w : A[lx].y;
        float t1x = odd ? Bv[lx].x : A[lx].z;
        float t1y = odd ? Bv[lx].y : A[lx].w;
        float t2x = odd ? Bv[lx].z : Bv[lx].x;
        float t2y = odd ? Bv[lx].w : Bv[lx].y;
        const float w0 = wx[lx] * wy[0];
        const float w1 = wx[lx] * wy[1];
        const float w2 = wx[lx] * wy[2];
        accx += t0x * w0 + t1x * w1 + t2x * w2;
        accy += t0y * w0 + t1y * w1 + t2y * w2;
    }
    const float s = sqrtf(dcf[(size_t)b * NM + m]);
    out[(size_t)b * NM + m] = make_float2(accx * s, accy * s);
}

extern "C" void kernel_launch(void* const* d_in, const int* in_sizes, int n_in,
                              void* d_out, int out_size, void* d_ws, size_t ws_size,
                              hipStream_t stream) {
    const float* x_re = (const float*)d_in[0];
    const float* x_im = (const float*)d_in[1];
    const float* traj = (const float*)d_in[2];
    const float* dcf  = (const float*)d_in[3];

    float2* buf1c = (float2*)d_ws;                          // [B][320][640] row-FFT (non-zero rows)
    float2* kbuf  = buf1c + (size_t)NB * NDIM * GDIM;       // [B][643][644] padded kgrid^T

    const double beta_d = M_PI * sqrt((1.5 * 1.5) * (1.5 * 1.5) - 0.8);
    const float beta = (float)beta_d;
    const float beta2 = (float)(beta_d * beta_d);

    dim3 gridA(NDIM, NB);
    pass_a<<<gridA, 320, 0, stream>>>(x_re, x_im, buf1c, beta2);

    dim3 gridB(GDIM / 4, NB);
    pass_b<<<gridB, 320, 0, stream>>>(buf1c, kbuf);

    gather_kernel<<<GBLK_PER_B * NB, 256, 0, stream>>>(traj, dcf, kbuf,
                                                       (float2*)d_out, beta);
}